// Round 1
// 2393.829 us; speedup vs baseline: 1.8243x; 1.8243x over previous
//
#include <hip/hip_runtime.h>
#include <hip/hip_bf16.h>
#include <stdint.h>

// B=128, T=25, V=10000, E=512, NF=2048, H=512, MAP=512, IN0=1024
// Round 6: replace the 100 tiny sequential GRU launches with ONE persistent
// kernel per layer (64 blocks, hand-rolled device-scope grid barrier).
// Gate weights live in LDS for all 25 steps; all LDS layouts are frag-major
// (staged via per-lane-source global_load_lds) so ds_read_b128 is conflict-free.

typedef __hip_bfloat16 bf16;
typedef __attribute__((ext_vector_type(8))) short frag8;   // 8 bf16 = 4 VGPR
typedef __attribute__((ext_vector_type(4))) float f32x4;

#define T_N 25

__device__ __forceinline__ float bf2f(bf16 x){ return __bfloat162float(x); }
__device__ __forceinline__ bf16 f2bf(float x){ return __float2bfloat16(x); }
__device__ __forceinline__ f32x4 mfma16(frag8 a, frag8 b, f32x4 c){
  return __builtin_amdgcn_mfma_f32_16x16x32_bf16(a, b, c, 0, 0, 0);
}
__device__ __forceinline__ void gld_lds16(const bf16* g, bf16* l){
  __builtin_amdgcn_global_load_lds((const __attribute__((address_space(1))) unsigned int*)g,
                                   (__attribute__((address_space(3))) unsigned int*)l, 16, 0, 0);
}
__device__ __forceinline__ float sigmoidf_(float x){ return 1.f/(1.f + __expf(-x)); }
__device__ __forceinline__ float tanhf_(float x){ return 2.f/(1.f + __expf(-2.f*x)) - 1.f; }

// ---------------- dtype detection ----------------
__global__ __launch_bounds__(256) void detect_kernel(const unsigned short* __restrict__ embu,
    const int* __restrict__ tok32, int* __restrict__ flags){
  __shared__ int cF, cT;
  if (threadIdx.x == 0){ cF = 0; cT = 0; }
  __syncthreads();
  int bad = 0;
  for (int j = threadIdx.x; j < 512; j += 256){
    unsigned e = (embu[2*j] >> 7) & 0xFFu;
    if (e > 160u) bad++;
  }
  if (bad) atomicAdd(&cF, bad);
  int nz = 0;
  for (int j = threadIdx.x; j < 128; j += 256)
    if (tok32[2*j + 1] != 0) nz++;
  if (nz) atomicAdd(&cT, nz);
  __syncthreads();
  if (threadIdx.x == 0){
    flags[0] = (cF > 8) ? 1 : 0;
    flags[1] = (cT < 4) ? 1 : 0;
  }
}

// ---------------- conversions ----------------
__global__ __launch_bounds__(256) void cvt_split(const void* __restrict__ src,
    bf16* __restrict__ hi, bf16* __restrict__ lo, int n, const int* __restrict__ flags){
  int i = (blockIdx.x*256 + threadIdx.x)*4;
  if (i >= n) return;
  bool isf = flags[0] != 0;
  #pragma unroll
  for (int j=0;j<4;j++){
    float x = isf ? ((const float*)src)[i+j] : bf2f(((const bf16*)src)[i+j]);
    bf16 h = f2bf(x);
    hi[i+j] = h;
    if (lo) lo[i+j] = f2bf(x - bf2f(h));
  }
}

struct CD { const void* src; float* dst; int n; };
struct CDs { CD d[8]; };
__global__ __launch_bounds__(256) void cvt_f32_batch(CDs all, const int* __restrict__ flags){
  CD d = all.d[blockIdx.y];
  int i = blockIdx.x*256 + threadIdx.x;
  if (i >= d.n) return;
  d.dst[i] = (flags[0] != 0) ? ((const float*)d.src)[i] : bf2f(((const bf16*)d.src)[i]);
}

// ---------------- init ----------------
__global__ __launch_bounds__(256) void init_zero(float* h0f, float* h1f,
    bf16* h0b, bf16* h0lb, bf16* h1b, bf16* h1lb, int* bar){
  int i = blockIdx.x*256 + threadIdx.x;
  if (blockIdx.x == 0 && threadIdx.x < 64) bar[threadIdx.x] = 0;
  if (i < 65536){
    h0f[i] = 0.f; h1f[i] = 0.f;
    bf16 z = f2bf(0.f);
    h0b[i] = z; h0lb[i] = z; h1b[i] = z; h1lb[i] = z;
  }
}

// ---------------- transpose + split ----------------
struct TD { const void* src; bf16* dh; bf16* dl; int k0, Kd, Nd, Ns, NsV; };
struct TDs { TD d[14]; };
__global__ __launch_bounds__(256) void transpose_many(TDs all, const int* __restrict__ flags){
  TD d = all.d[blockIdx.y];
  int tilesN = d.Nd >> 5, tilesK = d.Kd >> 5;
  if ((int)blockIdx.x >= tilesN*tilesK) return;
  bool isf = flags[0] != 0;
  int tn = blockIdx.x % tilesN, tk = blockIdx.x / tilesN;
  int nt0 = tn*32, kt0 = tk*32;
  __shared__ float tile[32][33];
  int tx = threadIdx.x & 31, ty = threadIdx.x >> 5;
  #pragma unroll
  for (int p=0;p<4;p++){
    int k = kt0 + ty + p*8, n = nt0 + tx;
    float v = 0.f;
    if (n < d.NsV){
      size_t idx = (size_t)(d.k0 + k)*d.Ns + n;
      v = isf ? ((const float*)d.src)[idx] : bf2f(((const bf16*)d.src)[idx]);
    }
    tile[ty + p*8][tx] = v;
  }
  __syncthreads();
  #pragma unroll
  for (int p=0;p<4;p++){
    int n = nt0 + ty + p*8, k = kt0 + tx;
    float v = tile[tx][ty + p*8];
    bf16 h = f2bf(v);
    d.dh[(size_t)n*d.Kd + k] = h;
    if (d.dl) d.dl[(size_t)n*d.Kd + k] = f2bf(v - bf2f(h));
  }
}

// ---------------- split GEMM (batched pre/post passes; unchanged) ----------------
template<int MODE>
__global__ __launch_bounds__(256) void gemm_split(
    const bf16* __restrict__ Ah, const bf16* __restrict__ Al,
    const bf16* __restrict__ Bth, const bf16* __restrict__ Btl,
    const float* __restrict__ bias, float* __restrict__ C,
    bf16* __restrict__ Ch, bf16* __restrict__ Cl, int K, int N)
{
  __shared__ bf16 Ash[128*32], Asl[128*32], Bsh[128*32], Bsl[128*32];
  const int m0 = blockIdx.y*128, n0 = blockIdx.x*128;
  const int tid = threadIdx.x, lane = tid & 63, wave = tid >> 6;
  const int wr = wave >> 1, wc = wave & 1, cl = lane & 15, cq = lane >> 4;
  f32x4 acc[4][4];
  #pragma unroll
  for (int i=0;i<4;i++)
    #pragma unroll
    for (int j=0;j<4;j++) acc[i][j] = (f32x4){0.f,0.f,0.f,0.f};

  const int r0 = tid >> 2, kc0 = (tid & 3)*8;
  for (int kt = 0; kt < K; kt += 32){
    gld_lds16(Ah  + (size_t)(m0 + r0)*K      + kt + kc0, Ash + (wave*64)*8);
    gld_lds16(Ah  + (size_t)(m0 + 64 + r0)*K + kt + kc0, Ash + (256 + wave*64)*8);
    gld_lds16(Al  + (size_t)(m0 + r0)*K      + kt + kc0, Asl + (wave*64)*8);
    gld_lds16(Al  + (size_t)(m0 + 64 + r0)*K + kt + kc0, Asl + (256 + wave*64)*8);
    gld_lds16(Bth + (size_t)(n0 + r0)*K      + kt + kc0, Bsh + (wave*64)*8);
    gld_lds16(Bth + (size_t)(n0 + 64 + r0)*K + kt + kc0, Bsh + (256 + wave*64)*8);
    gld_lds16(Btl + (size_t)(n0 + r0)*K      + kt + kc0, Bsl + (wave*64)*8);
    gld_lds16(Btl + (size_t)(n0 + 64 + r0)*K + kt + kc0, Bsl + (256 + wave*64)*8);
    __syncthreads();
    frag8 ah[4], al[4], bh[4], bl[4];
    #pragma unroll
    for (int i=0;i<4;i++){
      ah[i] = *(const frag8*)(Ash + (64*wr + 16*i + cl)*32 + cq*8);
      al[i] = *(const frag8*)(Asl + (64*wr + 16*i + cl)*32 + cq*8);
      bh[i] = *(const frag8*)(Bsh + (64*wc + 16*i + cl)*32 + cq*8);
      bl[i] = *(const frag8*)(Bsl + (64*wc + 16*i + cl)*32 + cq*8);
    }
    #pragma unroll
    for (int i=0;i<4;i++)
      #pragma unroll
      for (int j=0;j<4;j++){
        acc[i][j] = mfma16(ah[i], bh[j], acc[i][j]);
        acc[i][j] = mfma16(ah[i], bl[j], acc[i][j]);
        acc[i][j] = mfma16(al[i], bh[j], acc[i][j]);
      }
    __syncthreads();
  }
  #pragma unroll
  for (int j=0;j<4;j++){
    int col = n0 + 64*wc + 16*j + cl;
    float bv = bias[col];
    #pragma unroll
    for (int i=0;i<4;i++){
      int rowb = m0 + 64*wr + 16*i + cq*4;
      #pragma unroll
      for (int v=0;v<4;v++){
        float val = acc[i][j][v] + bv;
        int row = rowb + v;
        if (MODE == 1){
          val = (val > 0.f) ? val : 0.01f*val;
          bf16 h = f2bf(val);
          Ch[(size_t)row*N + col] = h;
          Cl[(size_t)row*N + col] = f2bf(val - bf2f(h));
        } else {
          C[(size_t)row*N + col] = val;
        }
      }
    }
  }
}

// ---------------- logits GEMM (unchanged) ----------------
__global__ __launch_bounds__(256) void gemm_logits(
    const bf16* __restrict__ A, const bf16* __restrict__ Bt,
    const float* __restrict__ bias, float* __restrict__ C, int K, int NV)
{
  __shared__ bf16 As[128*32];
  __shared__ bf16 Bs[128*32];
  const int m0 = blockIdx.y*128, n0 = blockIdx.x*128;
  const int tid = threadIdx.x, lane = tid & 63, wave = tid >> 6;
  const int wr = wave >> 1, wc = wave & 1, cl = lane & 15, cq = lane >> 4;
  f32x4 acc[4][4];
  #pragma unroll
  for (int i=0;i<4;i++)
    #pragma unroll
    for (int j=0;j<4;j++) acc[i][j] = (f32x4){0.f,0.f,0.f,0.f};
  const int r0 = tid >> 2, kc0 = (tid & 3)*8;
  for (int kt = 0; kt < K; kt += 32){
    gld_lds16(A  + (size_t)(m0 + r0)*K      + kt + kc0, As + (wave*64)*8);
    gld_lds16(A  + (size_t)(m0 + 64 + r0)*K + kt + kc0, As + (256 + wave*64)*8);
    gld_lds16(Bt + (size_t)(n0 + r0)*K      + kt + kc0, Bs + (wave*64)*8);
    gld_lds16(Bt + (size_t)(n0 + 64 + r0)*K + kt + kc0, Bs + (256 + wave*64)*8);
    __syncthreads();
    frag8 af[4], bfr[4];
    #pragma unroll
    for (int i=0;i<4;i++){
      af[i]  = *(const frag8*)(As + (64*wr + 16*i + cl)*32 + cq*8);
      bfr[i] = *(const frag8*)(Bs + (64*wc + 16*i + cl)*32 + cq*8);
    }
    #pragma unroll
    for (int i=0;i<4;i++)
      #pragma unroll
      for (int j=0;j<4;j++)
        acc[i][j] = mfma16(af[i], bfr[j], acc[i][j]);
    __syncthreads();
  }
  #pragma unroll
  for (int j=0;j<4;j++){
    int col = n0 + 64*wc + 16*j + cl;
    if (col >= NV) continue;
    float bv = bias[col];
    #pragma unroll
    for (int i=0;i<4;i++){
      int rowb = m0 + 64*wr + 16*i + cq*4;
      #pragma unroll
      for (int v=0;v<4;v++){
        int row = rowb + v;
        int b = row & 127, t = row >> 7;
        C[((size_t)b*T_N + t)*NV + col] = acc[i][j][v] + bv;
      }
    }
  }
}

// ---------------- X0A build (unchanged) ----------------
__global__ __launch_bounds__(256) void build_x0a(const int* __restrict__ tok32,
    const bf16* __restrict__ embH, const bf16* __restrict__ embL,
    const bf16* __restrict__ pH, const bf16* __restrict__ pL,
    bf16* __restrict__ XH, bf16* __restrict__ XL, const int* __restrict__ flags)
{
  int r = blockIdx.x;
  int t = r >> 7, b = r & 127;
  int idx = b*T_N + t;
  int tok = (flags[1] != 0) ? tok32[2*idx] : tok32[idx];
  int k = threadIdx.x * 4;
  uint2 hv, lv;
  if (k < 512){
    hv = *(const uint2*)(embH + (size_t)tok*512 + k);
    lv = *(const uint2*)(embL + (size_t)tok*512 + k);
  } else {
    hv = *(const uint2*)(pH + b*512 + (k - 512));
    lv = *(const uint2*)(pL + b*512 + (k - 512));
  }
  *(uint2*)(XH + (size_t)r*1024 + k) = hv;
  *(uint2*)(XL + (size_t)r*1024 + k) = lv;
}

// ================= persistent GRU layer =================
// Grid: 64 blocks x 256 threads. Block b owns gate cols [b*16, b*16+16) of the
// 1024 u|r cols (phase A); blocks 0..31 additionally own c cols [b*16,+16)
// (phase B). Wh slices stay in LDS for all 25 steps. All LDS layouts are
// frag-major: tile = 64 units of 16B; unit s holds (row = s&15, k = (s>>4)*8..+8),
// so ds_read_b128 fragment reads are conflict-free and global_load_lds's
// linear lane*16B destination matches (per-lane SOURCE addressing).

// stage a 16x512 weight slice: 16 tiles by k-chunk (32 k each)
__device__ __forceinline__ void stage_w(const bf16* __restrict__ src, bf16* dst,
                                        int wave, int lane){
  #pragma unroll
  for (int p=0;p<4;p++){
    int kc = p*4 + wave;                       // 0..15
    gld_lds16(src + (size_t)(lane & 15)*512 + kc*32 + ((lane >> 4)*8),
              dst + kc*512);
  }
}

// stage one BK=64 chunk of a [128][512] activation matrix (16 tiles: rg 0..7 x kkc 0..1)
__device__ __forceinline__ void stage_a(const bf16* __restrict__ src, bf16* dst,
                                        int wave, int lane, int c){
  #pragma unroll
  for (int p=0;p<4;p++){
    int tile = p*4 + wave;                     // 0..15 ; tile = rg*2 + kkc
    int rg = tile >> 1, kkc = tile & 1;
    gld_lds16(src + (size_t)(rg*16 + (lane & 15))*512 + c*64 + kkc*32 + ((lane >> 4)*8),
              dst + tile*512);
  }
}

__device__ __forceinline__ void compute_chunk(const bf16* SAh, const bf16* SAl,
    const bf16* WH, const bf16* WL, f32x4 acc[2], int wave, int lane, int c){
  #pragma unroll
  for (int kkc=0;kkc<2;kkc++){
    int kc = c*2 + kkc;
    frag8 bh = *(const frag8*)(WH + kc*512 + lane*8);
    frag8 bl = *(const frag8*)(WL + kc*512 + lane*8);
    #pragma unroll
    for (int il=0;il<2;il++){
      int tile = (wave*2 + il)*2 + kkc;
      frag8 ah = *(const frag8*)(SAh + tile*512 + lane*8);
      frag8 al = *(const frag8*)(SAl + tile*512 + lane*8);
      acc[il] = mfma16(ah, bh, acc[il]);
      acc[il] = mfma16(ah, bl, acc[il]);
      acc[il] = mfma16(al, bh, acc[il]);
    }
  }
}

// 128x16 GEMM, K=512, A from global (hi+lo), B resident in LDS, dbuf staging
__device__ __forceinline__ void gemm_16(const bf16* __restrict__ Ah, const bf16* __restrict__ Al,
    const bf16* WH, const bf16* WL,
    bf16* S0h, bf16* S0l, bf16* S1h, bf16* S1l,
    f32x4 acc[2], int wave, int lane)
{
  acc[0] = (f32x4){0.f,0.f,0.f,0.f};
  acc[1] = (f32x4){0.f,0.f,0.f,0.f};
  stage_a(Ah, S0h, wave, lane, 0);
  stage_a(Al, S0l, wave, lane, 0);
  #pragma unroll
  for (int c=0;c<8;c++){
    __syncthreads();                            // drains own vmcnt, then barrier
    const bf16* ch = (c & 1) ? S1h : S0h;
    const bf16* cl = (c & 1) ? S1l : S0l;
    if (c < 7){
      bf16* nh = (c & 1) ? S0h : S1h;
      bf16* nl = (c & 1) ? S0l : S1l;
      stage_a(Ah, nh, wave, lane, c+1);         // overlaps with compute below
      stage_a(Al, nl, wave, lane, c+1);
    }
    compute_chunk(ch, cl, WH, WL, acc, wave, lane, c);
  }
}

// sense-reversing device-scope grid barrier (thread 0 per block)
__device__ __forceinline__ void grid_barrier(int* cnt, int* gen, int nb){
  __syncthreads();
  if (threadIdx.x == 0){
    int g = __hip_atomic_load(gen, __ATOMIC_RELAXED, __HIP_MEMORY_SCOPE_AGENT);
    int prev = __hip_atomic_fetch_add(cnt, 1, __ATOMIC_ACQ_REL, __HIP_MEMORY_SCOPE_AGENT);
    if (prev == nb - 1){
      __hip_atomic_store(cnt, 0, __ATOMIC_RELAXED, __HIP_MEMORY_SCOPE_AGENT);
      __hip_atomic_store(gen, g + 1, __ATOMIC_RELEASE, __HIP_MEMORY_SCOPE_AGENT);
    } else {
      int cur;
      do {
        __builtin_amdgcn_s_sleep(2);
        cur = __hip_atomic_load(gen, __ATOMIC_ACQUIRE, __HIP_MEMORY_SCOPE_AGENT);
      } while (cur == g);
    }
  }
  __syncthreads();
}

__global__ __launch_bounds__(256, 1) void gru_layer(
    const bf16* __restrict__ Wh, const bf16* __restrict__ Wl,   // [1536][512] u|r|c
    const float* __restrict__ Xall,                             // [3200][1536]
    float* __restrict__ hf,
    bf16* __restrict__ hb, bf16* __restrict__ hlb,
    bf16* __restrict__ rhb, bf16* __restrict__ rhlb,
    float* __restrict__ uf,
    bf16* __restrict__ Hh, bf16* __restrict__ Hl,
    int* __restrict__ bar)
{
  __shared__ bf16 WAh_s[8192], WAl_s[8192];     // phase-A weight slice (16 cols)
  __shared__ bf16 WBh_s[8192], WBl_s[8192];     // phase-B weight slice (blocks<32)
  __shared__ bf16 S0h[8192], S0l[8192], S1h[8192], S1l[8192];  // staging dbuf
  const int tid = threadIdx.x, lane = tid & 63, wave = tid >> 6, blk = blockIdx.x;
  int* cnt = bar;
  int* gen = bar + 32;

  stage_w(Wh + (size_t)blk*16*512, WAh_s, wave, lane);
  stage_w(Wl + (size_t)blk*16*512, WAl_s, wave, lane);
  if (blk < 32){
    stage_w(Wh + (size_t)(1024 + blk*16)*512, WBh_s, wave, lane);
    stage_w(Wl + (size_t)(1024 + blk*16)*512, WBl_s, wave, lane);
  }
  // weight loads drain at gemm_16's first __syncthreads

  const int colL = lane & 15;
  const int colA = blk*16 + colL;               // 0..1023
  const bool is_u = (blk < 32);

  #pragma unroll 1
  for (int t = 0; t < T_N; t++){
    // ---- phase A: pre_ur = h @ Wh[u|r] + X ; u = sig ; rh = sig*h ----
    {
      f32x4 acc[2];
      gemm_16(hb, hlb, WAh_s, WAl_s, S0h, S0l, S1h, S1l, acc, wave, lane);
      int c2 = colA & 511;
      #pragma unroll
      for (int il=0; il<2; il++){
        int rowb = wave*32 + il*16 + (lane >> 4)*4;
        #pragma unroll
        for (int v=0; v<4; v++){
          int row = rowb + v;
          float val = acc[il][v] + Xall[(size_t)(t*128 + row)*1536 + colA];
          float s = sigmoidf_(val);
          size_t o = (size_t)row*512 + c2;
          if (is_u){
            uf[o] = s;
          } else {
            float rh = s * hf[o];
            bf16 h = f2bf(rh);
            rhb[o] = h; rhlb[o] = f2bf(rh - bf2f(h));
          }
        }
      }
    }
    grid_barrier(cnt, gen, 64);

    // ---- phase B: pre_c = (r*h) @ Wc + X ; h' = u*h + (1-u)*tanh(pre_c) ----
    if (blk < 32){
      f32x4 acc[2];
      gemm_16(rhb, rhlb, WBh_s, WBl_s, S0h, S0l, S1h, S1l, acc, wave, lane);
      #pragma unroll
      for (int il=0; il<2; il++){
        int rowb = wave*32 + il*16 + (lane >> 4)*4;
        #pragma unroll
        for (int v=0; v<4; v++){
          int row = rowb + v;
          float val = acc[il][v] + Xall[(size_t)(t*128 + row)*1536 + 1024 + colA];
          float hh = tanhf_(val);
          size_t o = (size_t)row*512 + colA;
          float u = uf[o], hold = hf[o];
          float hn = u*hold + (1.f - u)*hh;
          hf[o] = hn;
          bf16 hhi = f2bf(hn);
          bf16 hlo = f2bf(hn - bf2f(hhi));
          hb[o] = hhi; hlb[o] = hlo;
          size_t ot = (size_t)(t*128 + row)*512 + colA;
          Hh[ot] = hhi; Hl[ot] = hlo;
        }
      }
    }
    grid_barrier(cnt, gen, 64);
  }
}

// ---------------- hidden output (f32) ----------------
__global__ __launch_bounds__(256) void hidden_out(const float* __restrict__ h0f,
    const float* __restrict__ h1f, float* __restrict__ out){
  int i = blockIdx.x*256 + threadIdx.x;
  out[i] = (i < 65536) ? h0f[i] : h1f[i - 65536];
}

// ---------------- host ----------------
extern "C" void kernel_launch(void* const* d_in, const int* in_sizes, int n_in,
                              void* d_out, int out_size, void* d_ws, size_t ws_size,
                              hipStream_t stream)
{
  const void* tokens = d_in[0];
  const void* cnn  = d_in[1];
  const void* emb  = d_in[2];
  const void* Win  = d_in[3];
  const void* bin  = d_in[4];
  const void* Wout = d_in[5];
  const void* bout = d_in[6];
  const void* Wu0  = d_in[7];
  const void* bu0  = d_in[8];
  const void* Wr0  = d_in[9];
  const void* br0  = d_in[10];
  const void* Wc0  = d_in[11];
  const void* bc0  = d_in[12];
  const void* Wu1  = d_in[13];
  const void* bu1  = d_in[14];
  const void* Wr1  = d_in[15];
  const void* br1  = d_in[16];
  const void* Wc1  = d_in[17];
  const void* bc1  = d_in[18];

  char* wp = (char*)d_ws;
  auto alloc = [&](size_t bytes) -> char* {
    char* r = wp; wp += (bytes + 255) & ~(size_t)255; return r;
  };
  auto B2 = [](size_t n){ return n*2; };
  bf16* WinTh  = (bf16*)alloc(B2(512*2048)); bf16* WinTl  = (bf16*)alloc(B2(512*2048));
  bf16* WoutTh = (bf16*)alloc(B2((size_t)10112*512));
  bf16* W0xTh = (bf16*)alloc(B2((size_t)1536*1024)); bf16* W0xTl = (bf16*)alloc(B2((size_t)1536*1024));
  bf16* W0hTh = (bf16*)alloc(B2((size_t)1536*512));  bf16* W0hTl = (bf16*)alloc(B2((size_t)1536*512));
  bf16* W1xTh = (bf16*)alloc(B2((size_t)1536*512));  bf16* W1xTl = (bf16*)alloc(B2((size_t)1536*512));
  bf16* W1hTh = (bf16*)alloc(B2((size_t)1536*512));  bf16* W1hTl = (bf16*)alloc(B2((size_t)1536*512));
  bf16* embH = (bf16*)alloc(B2((size_t)10000*512));
  bf16* embL = (bf16*)alloc(B2((size_t)10000*512));
  bf16* cnnH = (bf16*)alloc(B2(128*2048)); bf16* cnnL = (bf16*)alloc(B2(128*2048));
  bf16* pH   = (bf16*)alloc(B2(128*512)); bf16* pL = (bf16*)alloc(B2(128*512));
  bf16* X0AH = (bf16*)alloc(B2((size_t)3200*1024)); bf16* X0AL = (bf16*)alloc(B2((size_t)3200*1024));
  float* Xall = (float*)alloc((size_t)3200*1536*4);
  bf16* H0h = (bf16*)alloc(B2((size_t)3200*512)); bf16* H0l = (bf16*)alloc(B2((size_t)3200*512));
  bf16* H1h = (bf16*)alloc(B2((size_t)3200*512)); bf16* H1l = (bf16*)alloc(B2((size_t)3200*512));
  float* binF = (float*)alloc(512*4);
  float* boutF = (float*)alloc(10000*4);
  float* b0all = (float*)alloc(1536*4);
  float* b1all = (float*)alloc(1536*4);
  float* h0f = (float*)alloc(65536*4); float* h1f = (float*)alloc(65536*4);
  float* uf0 = (float*)alloc(65536*4); float* uf1 = (float*)alloc(65536*4);
  bf16* h0b = (bf16*)alloc(B2(65536)); bf16* h0lb = (bf16*)alloc(B2(65536));
  bf16* h1b = (bf16*)alloc(B2(65536)); bf16* h1lb = (bf16*)alloc(B2(65536));
  bf16* rh0 = (bf16*)alloc(B2(65536)); bf16* rh0l = (bf16*)alloc(B2(65536));
  bf16* rh1 = (bf16*)alloc(B2(65536)); bf16* rh1l = (bf16*)alloc(B2(65536));
  int* flags = (int*)alloc(256);
  int* bar = (int*)alloc(256);

  detect_kernel<<<1, 256, 0, stream>>>((const unsigned short*)emb, (const int*)tokens, flags);
  cvt_split<<<5000, 256, 0, stream>>>(emb, embH, embL, 5120000, flags);
  cvt_split<<<256, 256, 0, stream>>>(cnn, cnnH, cnnL, 262144, flags);
  CDs cds;
  cds.d[0] = {bin,  binF,  512};
  cds.d[1] = {bout, boutF, 10000};
  cds.d[2] = {bu0,  b0all + 0,    512};
  cds.d[3] = {br0,  b0all + 512,  512};
  cds.d[4] = {bc0,  b0all + 1024, 512};
  cds.d[5] = {bu1,  b1all + 0,    512};
  cds.d[6] = {br1,  b1all + 512,  512};
  cds.d[7] = {bc1,  b1all + 1024, 512};
  cvt_f32_batch<<<dim3(40, 8), 256, 0, stream>>>(cds, flags);

  TDs tds;
  tds.d[0]  = {Win,  WinTh, WinTl, 0, 2048, 512, 512, 512};
  tds.d[1]  = {Wout, WoutTh, nullptr, 0, 512, 10112, 10000, 10000};
  tds.d[2]  = {Wu0, W0xTh,               W0xTl,               0,    1024, 512, 512, 512};
  tds.d[3]  = {Wr0, W0xTh + 512*1024,    W0xTl + 512*1024,    0,    1024, 512, 512, 512};
  tds.d[4]  = {Wc0, W0xTh + 1024*1024,   W0xTl + 1024*1024,   512,  1024, 512, 512, 512};
  tds.d[5]  = {Wu0, W0hTh,               W0hTl,               1024, 512,  512, 512, 512};
  tds.d[6]  = {Wr0, W0hTh + 512*512,     W0hTl + 512*512,     1024, 512,  512, 512, 512};
  tds.d[7]  = {Wc0, W0hTh + 1024*512,    W0hTl + 1024*512,    0,    512,  512, 512, 512};
  tds.d[8]  = {Wu1, W1xTh,               W1xTl,               0,    512,  512, 512, 512};
  tds.d[9]  = {Wr1, W1xTh + 512*512,     W1xTl + 512*512,     0,    512,  512, 512, 512};
  tds.d[10] = {Wc1, W1xTh + 1024*512,    W1xTl + 1024*512,    512,  512,  512, 512, 512};
  tds.d[11] = {Wu1, W1hTh,               W1hTl,               512,  512,  512, 512, 512};
  tds.d[12] = {Wr1, W1hTh + 512*512,     W1hTl + 512*512,     512,  512,  512, 512, 512};
  tds.d[13] = {Wc1, W1hTh + 1024*512,    W1hTl + 1024*512,    0,    512,  512, 512, 512};
  transpose_many<<<dim3(5056, 14), 256, 0, stream>>>(tds, flags);

  init_zero<<<256, 256, 0, stream>>>(h0f, h1f, h0b, h0lb, h1b, h1lb, bar);

  gemm_split<1><<<dim3(4, 1), 256, 0, stream>>>(
      cnnH, cnnL, WinTh, WinTl, binF, nullptr, pH, pL, 2048, 512);
  build_x0a<<<3200, 256, 0, stream>>>((const int*)tokens, embH, embL, pH, pL, X0AH, X0AL, flags);
  gemm_split<0><<<dim3(12, 25), 256, 0, stream>>>(
      X0AH, X0AL, W0xTh, W0xTl, b0all, Xall, nullptr, nullptr, 1024, 1536);

  gru_layer<<<64, 256, 0, stream>>>(W0hTh, W0hTl, Xall, h0f,
                                    h0b, h0lb, rh0, rh0l, uf0, H0h, H0l, bar);

  gemm_split<0><<<dim3(12, 25), 256, 0, stream>>>(
      H0h, H0l, W1xTh, W1xTl, b1all, Xall, nullptr, nullptr, 512, 1536);

  gru_layer<<<64, 256, 0, stream>>>(W1hTh, W1hTl, Xall, h1f,
                                    h1b, h1lb, rh1, rh1l, uf1, H1h, H1l, bar);

  float* out = (float*)d_out;
  gemm_logits<<<dim3(79, 25), 256, 0, stream>>>(H1h, WoutTh, boutF, out, 512, 10000);
  hidden_out<<<512, 256, 0, stream>>>(h0f, h1f, out + 32000000);
}

// Round 2
// 1709.144 us; speedup vs baseline: 2.5552x; 1.4006x over previous
//
#include <hip/hip_runtime.h>
#include <hip/hip_bf16.h>
#include <stdint.h>

// B=128, T=25, V=10000, E=512, NF=2048, H=512, MAP=512, IN0=1024
// Round 7: gru_layer rewritten — 32 blocks, all gate weights (u,r,c hi+lo =
// 96KB) LDS-resident; A-operand (h / r*h) loaded DIRECTLY to registers (64
// independent dwordx4 per thread, no LDS staging, no intra-phase syncthreads);
// u and h_old carried in registers across phases/steps (uf array eliminated,
// hf is write-once at t=24); Xall slices prefetched one phase ahead.

typedef __hip_bfloat16 bf16;
typedef __attribute__((ext_vector_type(8))) short frag8;   // 8 bf16 = 4 VGPR
typedef __attribute__((ext_vector_type(4))) float f32x4;

#define T_N 25

__device__ __forceinline__ float bf2f(bf16 x){ return __bfloat162float(x); }
__device__ __forceinline__ bf16 f2bf(float x){ return __float2bfloat16(x); }
__device__ __forceinline__ f32x4 mfma16(frag8 a, frag8 b, f32x4 c){
  return __builtin_amdgcn_mfma_f32_16x16x32_bf16(a, b, c, 0, 0, 0);
}
__device__ __forceinline__ void gld_lds16(const bf16* g, bf16* l){
  __builtin_amdgcn_global_load_lds((const __attribute__((address_space(1))) unsigned int*)g,
                                   (__attribute__((address_space(3))) unsigned int*)l, 16, 0, 0);
}
__device__ __forceinline__ float sigmoidf_(float x){ return 1.f/(1.f + __expf(-x)); }
__device__ __forceinline__ float tanhf_(float x){ return 2.f/(1.f + __expf(-2.f*x)) - 1.f; }

// ---------------- dtype detection ----------------
__global__ __launch_bounds__(256) void detect_kernel(const unsigned short* __restrict__ embu,
    const int* __restrict__ tok32, int* __restrict__ flags){
  __shared__ int cF, cT;
  if (threadIdx.x == 0){ cF = 0; cT = 0; }
  __syncthreads();
  int bad = 0;
  for (int j = threadIdx.x; j < 512; j += 256){
    unsigned e = (embu[2*j] >> 7) & 0xFFu;
    if (e > 160u) bad++;
  }
  if (bad) atomicAdd(&cF, bad);
  int nz = 0;
  for (int j = threadIdx.x; j < 128; j += 256)
    if (tok32[2*j + 1] != 0) nz++;
  if (nz) atomicAdd(&cT, nz);
  __syncthreads();
  if (threadIdx.x == 0){
    flags[0] = (cF > 8) ? 1 : 0;
    flags[1] = (cT < 4) ? 1 : 0;
  }
}

// ---------------- conversions ----------------
__global__ __launch_bounds__(256) void cvt_split(const void* __restrict__ src,
    bf16* __restrict__ hi, bf16* __restrict__ lo, int n, const int* __restrict__ flags){
  int i = (blockIdx.x*256 + threadIdx.x)*4;
  if (i >= n) return;
  bool isf = flags[0] != 0;
  #pragma unroll
  for (int j=0;j<4;j++){
    float x = isf ? ((const float*)src)[i+j] : bf2f(((const bf16*)src)[i+j]);
    bf16 h = f2bf(x);
    hi[i+j] = h;
    if (lo) lo[i+j] = f2bf(x - bf2f(h));
  }
}

struct CD { const void* src; float* dst; int n; };
struct CDs { CD d[8]; };
__global__ __launch_bounds__(256) void cvt_f32_batch(CDs all, const int* __restrict__ flags){
  CD d = all.d[blockIdx.y];
  int i = blockIdx.x*256 + threadIdx.x;
  if (i >= d.n) return;
  d.dst[i] = (flags[0] != 0) ? ((const float*)d.src)[i] : bf2f(((const bf16*)d.src)[i]);
}

// ---------------- init ----------------
__global__ __launch_bounds__(256) void init_zero(float* h0f, float* h1f,
    bf16* h0b, bf16* h0lb, bf16* h1b, bf16* h1lb, int* bar){
  int i = blockIdx.x*256 + threadIdx.x;
  if (blockIdx.x == 0 && threadIdx.x < 64) bar[threadIdx.x] = 0;
  if (i < 65536){
    h0f[i] = 0.f; h1f[i] = 0.f;
    bf16 z = f2bf(0.f);
    h0b[i] = z; h0lb[i] = z; h1b[i] = z; h1lb[i] = z;
  }
}

// ---------------- transpose + split ----------------
struct TD { const void* src; bf16* dh; bf16* dl; int k0, Kd, Nd, Ns, NsV; };
struct TDs { TD d[14]; };
__global__ __launch_bounds__(256) void transpose_many(TDs all, const int* __restrict__ flags){
  TD d = all.d[blockIdx.y];
  int tilesN = d.Nd >> 5, tilesK = d.Kd >> 5;
  if ((int)blockIdx.x >= tilesN*tilesK) return;
  bool isf = flags[0] != 0;
  int tn = blockIdx.x % tilesN, tk = blockIdx.x / tilesN;
  int nt0 = tn*32, kt0 = tk*32;
  __shared__ float tile[32][33];
  int tx = threadIdx.x & 31, ty = threadIdx.x >> 5;
  #pragma unroll
  for (int p=0;p<4;p++){
    int k = kt0 + ty + p*8, n = nt0 + tx;
    float v = 0.f;
    if (n < d.NsV){
      size_t idx = (size_t)(d.k0 + k)*d.Ns + n;
      v = isf ? ((const float*)d.src)[idx] : bf2f(((const bf16*)d.src)[idx]);
    }
    tile[ty + p*8][tx] = v;
  }
  __syncthreads();
  #pragma unroll
  for (int p=0;p<4;p++){
    int n = nt0 + ty + p*8, k = kt0 + tx;
    float v = tile[tx][ty + p*8];
    bf16 h = f2bf(v);
    d.dh[(size_t)n*d.Kd + k] = h;
    if (d.dl) d.dl[(size_t)n*d.Kd + k] = f2bf(v - bf2f(h));
  }
}

// ---------------- split GEMM (batched pre/post passes) ----------------
template<int MODE>
__global__ __launch_bounds__(256) void gemm_split(
    const bf16* __restrict__ Ah, const bf16* __restrict__ Al,
    const bf16* __restrict__ Bth, const bf16* __restrict__ Btl,
    const float* __restrict__ bias, float* __restrict__ C,
    bf16* __restrict__ Ch, bf16* __restrict__ Cl, int K, int N)
{
  __shared__ bf16 Ash[128*32], Asl[128*32], Bsh[128*32], Bsl[128*32];
  const int m0 = blockIdx.y*128, n0 = blockIdx.x*128;
  const int tid = threadIdx.x, lane = tid & 63, wave = tid >> 6;
  const int wr = wave >> 1, wc = wave & 1, cl = lane & 15, cq = lane >> 4;
  f32x4 acc[4][4];
  #pragma unroll
  for (int i=0;i<4;i++)
    #pragma unroll
    for (int j=0;j<4;j++) acc[i][j] = (f32x4){0.f,0.f,0.f,0.f};

  const int r0 = tid >> 2, kc0 = (tid & 3)*8;
  for (int kt = 0; kt < K; kt += 32){
    gld_lds16(Ah  + (size_t)(m0 + r0)*K      + kt + kc0, Ash + (wave*64)*8);
    gld_lds16(Ah  + (size_t)(m0 + 64 + r0)*K + kt + kc0, Ash + (256 + wave*64)*8);
    gld_lds16(Al  + (size_t)(m0 + r0)*K      + kt + kc0, Asl + (wave*64)*8);
    gld_lds16(Al  + (size_t)(m0 + 64 + r0)*K + kt + kc0, Asl + (256 + wave*64)*8);
    gld_lds16(Bth + (size_t)(n0 + r0)*K      + kt + kc0, Bsh + (wave*64)*8);
    gld_lds16(Bth + (size_t)(n0 + 64 + r0)*K + kt + kc0, Bsh + (256 + wave*64)*8);
    gld_lds16(Btl + (size_t)(n0 + r0)*K      + kt + kc0, Bsl + (wave*64)*8);
    gld_lds16(Btl + (size_t)(n0 + 64 + r0)*K + kt + kc0, Bsl + (256 + wave*64)*8);
    __syncthreads();
    frag8 ah[4], al[4], bh[4], bl[4];
    #pragma unroll
    for (int i=0;i<4;i++){
      ah[i] = *(const frag8*)(Ash + (64*wr + 16*i + cl)*32 + cq*8);
      al[i] = *(const frag8*)(Asl + (64*wr + 16*i + cl)*32 + cq*8);
      bh[i] = *(const frag8*)(Bsh + (64*wc + 16*i + cl)*32 + cq*8);
      bl[i] = *(const frag8*)(Bsl + (64*wc + 16*i + cl)*32 + cq*8);
    }
    #pragma unroll
    for (int i=0;i<4;i++)
      #pragma unroll
      for (int j=0;j<4;j++){
        acc[i][j] = mfma16(ah[i], bh[j], acc[i][j]);
        acc[i][j] = mfma16(ah[i], bl[j], acc[i][j]);
        acc[i][j] = mfma16(al[i], bh[j], acc[i][j]);
      }
    __syncthreads();
  }
  #pragma unroll
  for (int j=0;j<4;j++){
    int col = n0 + 64*wc + 16*j + cl;
    float bv = bias[col];
    #pragma unroll
    for (int i=0;i<4;i++){
      int rowb = m0 + 64*wr + 16*i + cq*4;
      #pragma unroll
      for (int v=0;v<4;v++){
        float val = acc[i][j][v] + bv;
        int row = rowb + v;
        if (MODE == 1){
          val = (val > 0.f) ? val : 0.01f*val;
          bf16 h = f2bf(val);
          Ch[(size_t)row*N + col] = h;
          Cl[(size_t)row*N + col] = f2bf(val - bf2f(h));
        } else {
          C[(size_t)row*N + col] = val;
        }
      }
    }
  }
}

// ---------------- logits GEMM ----------------
__global__ __launch_bounds__(256) void gemm_logits(
    const bf16* __restrict__ A, const bf16* __restrict__ Bt,
    const float* __restrict__ bias, float* __restrict__ C, int K, int NV)
{
  __shared__ bf16 As[128*32];
  __shared__ bf16 Bs[128*32];
  const int m0 = blockIdx.y*128, n0 = blockIdx.x*128;
  const int tid = threadIdx.x, lane = tid & 63, wave = tid >> 6;
  const int wr = wave >> 1, wc = wave & 1, cl = lane & 15, cq = lane >> 4;
  f32x4 acc[4][4];
  #pragma unroll
  for (int i=0;i<4;i++)
    #pragma unroll
    for (int j=0;j<4;j++) acc[i][j] = (f32x4){0.f,0.f,0.f,0.f};
  const int r0 = tid >> 2, kc0 = (tid & 3)*8;
  for (int kt = 0; kt < K; kt += 32){
    gld_lds16(A  + (size_t)(m0 + r0)*K      + kt + kc0, As + (wave*64)*8);
    gld_lds16(A  + (size_t)(m0 + 64 + r0)*K + kt + kc0, As + (256 + wave*64)*8);
    gld_lds16(Bt + (size_t)(n0 + r0)*K      + kt + kc0, Bs + (wave*64)*8);
    gld_lds16(Bt + (size_t)(n0 + 64 + r0)*K + kt + kc0, Bs + (256 + wave*64)*8);
    __syncthreads();
    frag8 af[4], bfr[4];
    #pragma unroll
    for (int i=0;i<4;i++){
      af[i]  = *(const frag8*)(As + (64*wr + 16*i + cl)*32 + cq*8);
      bfr[i] = *(const frag8*)(Bs + (64*wc + 16*i + cl)*32 + cq*8);
    }
    #pragma unroll
    for (int i=0;i<4;i++)
      #pragma unroll
      for (int j=0;j<4;j++)
        acc[i][j] = mfma16(af[i], bfr[j], acc[i][j]);
    __syncthreads();
  }
  #pragma unroll
  for (int j=0;j<4;j++){
    int col = n0 + 64*wc + 16*j + cl;
    if (col >= NV) continue;
    float bv = bias[col];
    #pragma unroll
    for (int i=0;i<4;i++){
      int rowb = m0 + 64*wr + 16*i + cq*4;
      #pragma unroll
      for (int v=0;v<4;v++){
        int row = rowb + v;
        int b = row & 127, t = row >> 7;
        C[((size_t)b*T_N + t)*NV + col] = acc[i][j][v] + bv;
      }
    }
  }
}

// ---------------- X0A build ----------------
__global__ __launch_bounds__(256) void build_x0a(const int* __restrict__ tok32,
    const bf16* __restrict__ embH, const bf16* __restrict__ embL,
    const bf16* __restrict__ pH, const bf16* __restrict__ pL,
    bf16* __restrict__ XH, bf16* __restrict__ XL, const int* __restrict__ flags)
{
  int r = blockIdx.x;
  int t = r >> 7, b = r & 127;
  int idx = b*T_N + t;
  int tok = (flags[1] != 0) ? tok32[2*idx] : tok32[idx];
  int k = threadIdx.x * 4;
  uint2 hv, lv;
  if (k < 512){
    hv = *(const uint2*)(embH + (size_t)tok*512 + k);
    lv = *(const uint2*)(embL + (size_t)tok*512 + k);
  } else {
    hv = *(const uint2*)(pH + b*512 + (k - 512));
    lv = *(const uint2*)(pL + b*512 + (k - 512));
  }
  *(uint2*)(XH + (size_t)r*1024 + k) = hv;
  *(uint2*)(XL + (size_t)r*1024 + k) = lv;
}

// ================= persistent GRU layer (round 7) =================
// 32 blocks x 256 threads. Block b owns cols [b*16, b*16+16) of ALL THREE
// gates (u, r, c). Weight slices (6 x 16KB = 96KB) LDS-resident for all 25
// steps. A-operand read directly global->registers (no LDS staging, no
// intra-phase syncs). u and h_old live in registers across phases & steps.

// stage a 16x512 weight slice, frag-major (tile kc holds rows 0..15 x k 32)
__device__ __forceinline__ void stage_w(const bf16* __restrict__ src, bf16* dst,
                                        int wave, int lane){
  #pragma unroll
  for (int p=0;p<4;p++){
    int kc = p*4 + wave;                       // 0..15
    gld_lds16(src + (size_t)(lane & 15)*512 + kc*32 + ((lane >> 4)*8),
              dst + kc*512);
  }
}

// sense-reversing device-scope grid barrier (thread 0 per block)
__device__ __forceinline__ void grid_barrier(int* cnt, int* gen, int nb){
  __syncthreads();
  if (threadIdx.x == 0){
    int g = __hip_atomic_load(gen, __ATOMIC_RELAXED, __HIP_MEMORY_SCOPE_AGENT);
    int prev = __hip_atomic_fetch_add(cnt, 1, __ATOMIC_ACQ_REL, __HIP_MEMORY_SCOPE_AGENT);
    if (prev == nb - 1){
      __hip_atomic_store(cnt, 0, __ATOMIC_RELAXED, __HIP_MEMORY_SCOPE_AGENT);
      __hip_atomic_store(gen, g + 1, __ATOMIC_RELEASE, __HIP_MEMORY_SCOPE_AGENT);
    } else {
      int cur;
      do {
        __builtin_amdgcn_s_sleep(2);
        cur = __hip_atomic_load(gen, __ATOMIC_ACQUIRE, __HIP_MEMORY_SCOPE_AGENT);
      } while (cur == g);
    }
  }
  __syncthreads();
}

__global__ __launch_bounds__(256, 1) void gru_layer(
    const bf16* __restrict__ Wh, const bf16* __restrict__ Wl,   // [1536][512] u|r|c
    const float* __restrict__ Xall,                             // [3200][1536]
    float* __restrict__ hf,                                     // final h (t=24 only)
    bf16* __restrict__ hb, bf16* __restrict__ hlb,
    bf16* __restrict__ rhb, bf16* __restrict__ rhlb,
    bf16* __restrict__ Hh, bf16* __restrict__ Hl,
    int* __restrict__ bar)
{
  __shared__ bf16 WU_h[8192], WU_l[8192];
  __shared__ bf16 WR_h[8192], WR_l[8192];
  __shared__ bf16 WC_h[8192], WC_l[8192];
  const int tid = threadIdx.x, lane = tid & 63, wave = tid >> 6, blk = blockIdx.x;
  const int cl = lane & 15, cq = lane >> 4;
  int* cnt = bar;
  int* gen = bar + 32;

  stage_w(Wh + (size_t)(blk*16)*512,        WU_h, wave, lane);
  stage_w(Wl + (size_t)(blk*16)*512,        WU_l, wave, lane);
  stage_w(Wh + (size_t)(512 + blk*16)*512,  WR_h, wave, lane);
  stage_w(Wl + (size_t)(512 + blk*16)*512,  WR_l, wave, lane);
  stage_w(Wh + (size_t)(1024 + blk*16)*512, WC_h, wave, lane);
  stage_w(Wl + (size_t)(1024 + blk*16)*512, WC_l, wave, lane);
  __syncthreads();   // drains weight loads; LDS read-only afterwards

  const int col = blk*16 + cl;
  const size_t abase = (size_t)(wave*32 + cl)*512 + cq*8;   // + il*16*512 + kc*32

  float hold[2][4], ureg[2][4];
  float xu[2][4], xr[2][4], xc[2][4];
  #pragma unroll
  for (int il=0;il<2;il++)
    #pragma unroll
    for (int v=0;v<4;v++){
      hold[il][v] = 0.f;
      int row = wave*32 + il*16 + cq*4 + v;
      xu[il][v] = Xall[(size_t)row*1536 + col];          // t=0 prefetch
      xr[il][v] = Xall[(size_t)row*1536 + 512 + col];
    }

  #pragma unroll 1
  for (int t = 0; t < T_N; t++){
    // ---- phase A: u = sig(h@Wu + Xu); rh = sig(h@Wr + Xr) * h ----
    {
      frag8 AH[16][2], AL[16][2];
      #pragma unroll
      for (int kc=0;kc<16;kc++)
        #pragma unroll
        for (int il=0;il<2;il++){
          AH[kc][il] = *(const frag8*)(hb  + abase + il*16*512 + kc*32);
          AL[kc][il] = *(const frag8*)(hlb + abase + il*16*512 + kc*32);
        }
      // prefetch Xc for this t (independent of barrier data)
      #pragma unroll
      for (int il=0;il<2;il++)
        #pragma unroll
        for (int v=0;v<4;v++){
          int row = t*128 + wave*32 + il*16 + cq*4 + v;
          xc[il][v] = Xall[(size_t)row*1536 + 1024 + col];
        }
      f32x4 aU[2], aR[2];
      aU[0] = aU[1] = aR[0] = aR[1] = (f32x4){0.f,0.f,0.f,0.f};
      #pragma unroll
      for (int kc=0;kc<16;kc++){
        frag8 wuh = *(const frag8*)(WU_h + kc*512 + lane*8);
        frag8 wul = *(const frag8*)(WU_l + kc*512 + lane*8);
        frag8 wrh = *(const frag8*)(WR_h + kc*512 + lane*8);
        frag8 wrl = *(const frag8*)(WR_l + kc*512 + lane*8);
        #pragma unroll
        for (int il=0;il<2;il++){
          aU[il] = mfma16(AH[kc][il], wuh, aU[il]);
          aU[il] = mfma16(AH[kc][il], wul, aU[il]);
          aU[il] = mfma16(AL[kc][il], wuh, aU[il]);
          aR[il] = mfma16(AH[kc][il], wrh, aR[il]);
          aR[il] = mfma16(AH[kc][il], wrl, aR[il]);
          aR[il] = mfma16(AL[kc][il], wrh, aR[il]);
        }
      }
      #pragma unroll
      for (int il=0;il<2;il++)
        #pragma unroll
        for (int v=0;v<4;v++){
          int row = wave*32 + il*16 + cq*4 + v;
          float u = sigmoidf_(aU[il][v] + xu[il][v]);
          ureg[il][v] = u;
          float rh = sigmoidf_(aR[il][v] + xr[il][v]) * hold[il][v];
          size_t o = (size_t)row*512 + col;
          bf16 h = f2bf(rh);
          rhb[o] = h; rhlb[o] = f2bf(rh - bf2f(h));
        }
    }
    grid_barrier(cnt, gen, 32);

    // ---- phase B: h' = u*h + (1-u)*tanh((r*h)@Wc + Xc) ----
    {
      frag8 AH[16][2], AL[16][2];
      #pragma unroll
      for (int kc=0;kc<16;kc++)
        #pragma unroll
        for (int il=0;il<2;il++){
          AH[kc][il] = *(const frag8*)(rhb  + abase + il*16*512 + kc*32);
          AL[kc][il] = *(const frag8*)(rhlb + abase + il*16*512 + kc*32);
        }
      // prefetch Xu/Xr for t+1
      int t2 = (t+1 < T_N) ? t+1 : t;
      #pragma unroll
      for (int il=0;il<2;il++)
        #pragma unroll
        for (int v=0;v<4;v++){
          int row = t2*128 + wave*32 + il*16 + cq*4 + v;
          xu[il][v] = Xall[(size_t)row*1536 + col];
          xr[il][v] = Xall[(size_t)row*1536 + 512 + col];
        }
      f32x4 aC[2];
      aC[0] = aC[1] = (f32x4){0.f,0.f,0.f,0.f};
      #pragma unroll
      for (int kc=0;kc<16;kc++){
        frag8 wch = *(const frag8*)(WC_h + kc*512 + lane*8);
        frag8 wcl = *(const frag8*)(WC_l + kc*512 + lane*8);
        #pragma unroll
        for (int il=0;il<2;il++){
          aC[il] = mfma16(AH[kc][il], wch, aC[il]);
          aC[il] = mfma16(AH[kc][il], wcl, aC[il]);
          aC[il] = mfma16(AL[kc][il], wch, aC[il]);
        }
      }
      #pragma unroll
      for (int il=0;il<2;il++)
        #pragma unroll
        for (int v=0;v<4;v++){
          int row = wave*32 + il*16 + cq*4 + v;
          float hh = tanhf_(aC[il][v] + xc[il][v]);
          float u = ureg[il][v];
          float hn = u*hold[il][v] + (1.f - u)*hh;
          hold[il][v] = hn;
          size_t o = (size_t)row*512 + col;
          bf16 hhi = f2bf(hn), hlo = f2bf(hn - bf2f(hhi));
          hb[o] = hhi; hlb[o] = hlo;
          size_t ot = (size_t)(t*128 + row)*512 + col;
          Hh[ot] = hhi; Hl[ot] = hlo;
          if (t == T_N-1) hf[o] = hn;
        }
    }
    grid_barrier(cnt, gen, 32);
  }
}

// ---------------- hidden output (f32) ----------------
__global__ __launch_bounds__(256) void hidden_out(const float* __restrict__ h0f,
    const float* __restrict__ h1f, float* __restrict__ out){
  int i = blockIdx.x*256 + threadIdx.x;
  out[i] = (i < 65536) ? h0f[i] : h1f[i - 65536];
}

// ---------------- host ----------------
extern "C" void kernel_launch(void* const* d_in, const int* in_sizes, int n_in,
                              void* d_out, int out_size, void* d_ws, size_t ws_size,
                              hipStream_t stream)
{
  const void* tokens = d_in[0];
  const void* cnn  = d_in[1];
  const void* emb  = d_in[2];
  const void* Win  = d_in[3];
  const void* bin  = d_in[4];
  const void* Wout = d_in[5];
  const void* bout = d_in[6];
  const void* Wu0  = d_in[7];
  const void* bu0  = d_in[8];
  const void* Wr0  = d_in[9];
  const void* br0  = d_in[10];
  const void* Wc0  = d_in[11];
  const void* bc0  = d_in[12];
  const void* Wu1  = d_in[13];
  const void* bu1  = d_in[14];
  const void* Wr1  = d_in[15];
  const void* br1  = d_in[16];
  const void* Wc1  = d_in[17];
  const void* bc1  = d_in[18];

  char* wp = (char*)d_ws;
  auto alloc = [&](size_t bytes) -> char* {
    char* r = wp; wp += (bytes + 255) & ~(size_t)255; return r;
  };
  auto B2 = [](size_t n){ return n*2; };
  bf16* WinTh  = (bf16*)alloc(B2(512*2048)); bf16* WinTl  = (bf16*)alloc(B2(512*2048));
  bf16* WoutTh = (bf16*)alloc(B2((size_t)10112*512));
  bf16* W0xTh = (bf16*)alloc(B2((size_t)1536*1024)); bf16* W0xTl = (bf16*)alloc(B2((size_t)1536*1024));
  bf16* W0hTh = (bf16*)alloc(B2((size_t)1536*512));  bf16* W0hTl = (bf16*)alloc(B2((size_t)1536*512));
  bf16* W1xTh = (bf16*)alloc(B2((size_t)1536*512));  bf16* W1xTl = (bf16*)alloc(B2((size_t)1536*512));
  bf16* W1hTh = (bf16*)alloc(B2((size_t)1536*512));  bf16* W1hTl = (bf16*)alloc(B2((size_t)1536*512));
  bf16* embH = (bf16*)alloc(B2((size_t)10000*512));
  bf16* embL = (bf16*)alloc(B2((size_t)10000*512));
  bf16* cnnH = (bf16*)alloc(B2(128*2048)); bf16* cnnL = (bf16*)alloc(B2(128*2048));
  bf16* pH   = (bf16*)alloc(B2(128*512)); bf16* pL = (bf16*)alloc(B2(128*512));
  bf16* X0AH = (bf16*)alloc(B2((size_t)3200*1024)); bf16* X0AL = (bf16*)alloc(B2((size_t)3200*1024));
  float* Xall = (float*)alloc((size_t)3200*1536*4);
  bf16* H0h = (bf16*)alloc(B2((size_t)3200*512)); bf16* H0l = (bf16*)alloc(B2((size_t)3200*512));
  bf16* H1h = (bf16*)alloc(B2((size_t)3200*512)); bf16* H1l = (bf16*)alloc(B2((size_t)3200*512));
  float* binF = (float*)alloc(512*4);
  float* boutF = (float*)alloc(10000*4);
  float* b0all = (float*)alloc(1536*4);
  float* b1all = (float*)alloc(1536*4);
  float* h0f = (float*)alloc(65536*4); float* h1f = (float*)alloc(65536*4);
  bf16* h0b = (bf16*)alloc(B2(65536)); bf16* h0lb = (bf16*)alloc(B2(65536));
  bf16* h1b = (bf16*)alloc(B2(65536)); bf16* h1lb = (bf16*)alloc(B2(65536));
  bf16* rh0 = (bf16*)alloc(B2(65536)); bf16* rh0l = (bf16*)alloc(B2(65536));
  bf16* rh1 = (bf16*)alloc(B2(65536)); bf16* rh1l = (bf16*)alloc(B2(65536));
  int* flags = (int*)alloc(256);
  int* bar = (int*)alloc(256);

  detect_kernel<<<1, 256, 0, stream>>>((const unsigned short*)emb, (const int*)tokens, flags);
  cvt_split<<<5000, 256, 0, stream>>>(emb, embH, embL, 5120000, flags);
  cvt_split<<<256, 256, 0, stream>>>(cnn, cnnH, cnnL, 262144, flags);
  CDs cds;
  cds.d[0] = {bin,  binF,  512};
  cds.d[1] = {bout, boutF, 10000};
  cds.d[2] = {bu0,  b0all + 0,    512};
  cds.d[3] = {br0,  b0all + 512,  512};
  cds.d[4] = {bc0,  b0all + 1024, 512};
  cds.d[5] = {bu1,  b1all + 0,    512};
  cds.d[6] = {br1,  b1all + 512,  512};
  cds.d[7] = {bc1,  b1all + 1024, 512};
  cvt_f32_batch<<<dim3(40, 8), 256, 0, stream>>>(cds, flags);

  TDs tds;
  tds.d[0]  = {Win,  WinTh, WinTl, 0, 2048, 512, 512, 512};
  tds.d[1]  = {Wout, WoutTh, nullptr, 0, 512, 10112, 10000, 10000};
  tds.d[2]  = {Wu0, W0xTh,               W0xTl,               0,    1024, 512, 512, 512};
  tds.d[3]  = {Wr0, W0xTh + 512*1024,    W0xTl + 512*1024,    0,    1024, 512, 512, 512};
  tds.d[4]  = {Wc0, W0xTh + 1024*1024,   W0xTl + 1024*1024,   512,  1024, 512, 512, 512};
  tds.d[5]  = {Wu0, W0hTh,               W0hTl,               1024, 512,  512, 512, 512};
  tds.d[6]  = {Wr0, W0hTh + 512*512,     W0hTl + 512*512,     1024, 512,  512, 512, 512};
  tds.d[7]  = {Wc0, W0hTh + 1024*512,    W0hTl + 1024*512,    0,    512,  512, 512, 512};
  tds.d[8]  = {Wu1, W1xTh,               W1xTl,               0,    512,  512, 512, 512};
  tds.d[9]  = {Wr1, W1xTh + 512*512,     W1xTl + 512*512,     0,    512,  512, 512, 512};
  tds.d[10] = {Wc1, W1xTh + 1024*512,    W1xTl + 1024*512,    512,  512,  512, 512, 512};
  tds.d[11] = {Wu1, W1hTh,               W1hTl,               512,  512,  512, 512, 512};
  tds.d[12] = {Wr1, W1hTh + 512*512,     W1hTl + 512*512,     512,  512,  512, 512, 512};
  tds.d[13] = {Wc1, W1hTh + 1024*512,    W1hTl + 1024*512,    0,    512,  512, 512, 512};
  transpose_many<<<dim3(5056, 14), 256, 0, stream>>>(tds, flags);

  init_zero<<<256, 256, 0, stream>>>(h0f, h1f, h0b, h0lb, h1b, h1lb, bar);

  gemm_split<1><<<dim3(4, 1), 256, 0, stream>>>(
      cnnH, cnnL, WinTh, WinTl, binF, nullptr, pH, pL, 2048, 512);
  build_x0a<<<3200, 256, 0, stream>>>((const int*)tokens, embH, embL, pH, pL, X0AH, X0AL, flags);
  gemm_split<0><<<dim3(12, 25), 256, 0, stream>>>(
      X0AH, X0AL, W0xTh, W0xTl, b0all, Xall, nullptr, nullptr, 1024, 1536);

  gru_layer<<<32, 256, 0, stream>>>(W0hTh, W0hTl, Xall, h0f,
                                    h0b, h0lb, rh0, rh0l, H0h, H0l, bar);

  gemm_split<0><<<dim3(12, 25), 256, 0, stream>>>(
      H0h, H0l, W1xTh, W1xTl, b1all, Xall, nullptr, nullptr, 512, 1536);

  gru_layer<<<32, 256, 0, stream>>>(W1hTh, W1hTl, Xall, h1f,
                                    h1b, h1lb, rh1, rh1l, H1h, H1l, bar);

  float* out = (float*)d_out;
  gemm_logits<<<dim3(79, 25), 256, 0, stream>>>(H1h, WoutTh, boutF, out, 512, 10000);
  hidden_out<<<512, 256, 0, stream>>>(h0f, h1f, out + 32000000);
}